// Round 11
// baseline (242.226 us; speedup 1.0000x reference)
//
#include <hip/hip_runtime.h>

#define BATCH 2
#define NBOX 500
#define CH 512
#define HFD 25
#define IW 26
#define IRC 676            // 26*26
#define IRCP2 768          // padded channel stride (covers rc-tile overreach)
#define PPOOL 7
#define NP 49
#define NCLS 20
#define NO 101             // 80 loc + 21 score
#define OP2 112            // o padded to 7*16
#define MFRAG 7
#define KD 25088
#define FDIM 4096
#define NSTEP_TOT 128      // FDIM/32
#define FSPLIT 2
#define WCSTEPS 64         // steps per f-chunk = 2048/32
#define S_WC ((size_t)KD * OP2)   // 2,809,856
#define NFRAG_H (NP * 16 * MFRAG) // 5488 fragments per table for k_h

typedef __attribute__((ext_vector_type(4))) float f32x4;
typedef __attribute__((ext_vector_type(8))) short bf16x8;
typedef __attribute__((ext_vector_type(4))) unsigned int u32v4;

#define MFMA16 __builtin_amdgcn_mfma_f32_16x16x32_bf16

typedef __attribute__((address_space(1))) const unsigned int guint;
typedef __attribute__((address_space(3))) unsigned int luint;
#define GLL16(G, L) __builtin_amdgcn_global_load_lds((guint*)(G), (luint*)(L), 16, 0, 0)

// ---- 2-way split of an fp32 pair: hi = trunc-bf16(v), mid = RN-bf16(v-hi).
#define SPLIT2PK(V0, V1, HW, MW)                                       \
  {                                                                    \
    unsigned u0_ = __float_as_uint(V0), u1_ = __float_as_uint(V1);     \
    HW = (u0_ >> 16) | (u1_ & 0xffff0000u);                            \
    float r0_ = (V0) - __uint_as_float(u0_ & 0xffff0000u);             \
    float r1_ = (V1) - __uint_as_float(u1_ & 0xffff0000u);             \
    unsigned m0_ = __float_as_uint(r0_), m1_ = __float_as_uint(r1_);   \
    m0_ += 0x7fffu + ((m0_ >> 16) & 1u);                               \
    m1_ += 0x7fffu + ((m1_ >> 16) & 1u);                               \
    MW = (m0_ >> 16) | (m1_ & 0xffff0000u);                            \
  }

// ---- cheap variant: hi trunc, mid = trunc-bf16(v-hi); |rho| <= 2^-16|v| ----
#define SPLIT2T(V0, V1, HW, MW)                                        \
  {                                                                    \
    unsigned u0_ = __float_as_uint(V0), u1_ = __float_as_uint(V1);     \
    HW = (u0_ >> 16) | (u1_ & 0xffff0000u);                            \
    float r0_ = (V0) - __uint_as_float(u0_ & 0xffff0000u);             \
    float r1_ = (V1) - __uint_as_float(u1_ & 0xffff0000u);             \
    MW = (__float_as_uint(r0_) >> 16) |                                \
         (__float_as_uint(r1_) & 0xffff0000u);                         \
  }

// ---- exact 3-way truncation split (24-bit mantissa = 8+8+8) ----
#define SPLIT3PK(V0, V1, HW, MW, LW)                                   \
  {                                                                    \
    unsigned u0_ = __float_as_uint(V0), u1_ = __float_as_uint(V1);     \
    HW = (u0_ >> 16) | (u1_ & 0xffff0000u);                            \
    float r0_ = (V0) - __uint_as_float(u0_ & 0xffff0000u);             \
    float r1_ = (V1) - __uint_as_float(u1_ & 0xffff0000u);             \
    unsigned m0_ = __float_as_uint(r0_), m1_ = __float_as_uint(r1_);   \
    MW = (m0_ >> 16) | (m1_ & 0xffff0000u);                            \
    float s0_ = r0_ - __uint_as_float(m0_ & 0xffff0000u);              \
    float s1_ = r1_ - __uint_as_float(m1_ & 0xffff0000u);              \
    LW = (__float_as_uint(s0_) >> 16) |                                \
         (__float_as_uint(s1_) & 0xffff0000u);                         \
  }

// ---------------- A-tables: L=[l_w;s_w] -> MFMA A-frags, 2-way split -------
// Ahi[(mf*128 + s)*64 + lane] = 8 bf16 = A[o=mf*16+(l&15)][f=s*32+(l>>4)*8+j]
__global__ void k_lt(const float* __restrict__ lw, const float* __restrict__ sw,
                     u32v4* __restrict__ Ahi, u32v4* __restrict__ Amd) {
    int t = blockIdx.x * 256 + threadIdx.x;
    if (t >= MFRAG * NSTEP_TOT * 64) return;
    int lane = t & 63;
    int wv = t >> 6;                 // (mf*128 + s)
    int s = wv & 127, mf = wv >> 7;
    int o = mf * 16 + (lane & 15);
    int f0 = s * 32 + (lane >> 4) * 8;
    float v[8];
    const float* row = nullptr;
    if (o < 80) row = lw + (size_t)o * FDIM;
    else if (o < NO) row = sw + (size_t)(o - 80) * FDIM;
    #pragma unroll
    for (int j = 0; j < 8; ++j) v[j] = row ? row[f0 + j] : 0.f;
    u32v4 hw, mw;
    #pragma unroll
    for (int w = 0; w < 4; ++w)
        SPLIT2PK(v[2 * w], v[2 * w + 1], hw[w], mw[w]);
    Ahi[(size_t)wv * 64 + lane] = hw;
    Amd[(size_t)wv * 64 + lane] = mw;
}

// ---------------- integral image, c-major, padded stride 768 ---------------
__global__ void k_integral(const float* __restrict__ fm, float* __restrict__ I) {
    int gtid = blockIdx.x * blockDim.x + threadIdx.x;
    int wid = gtid >> 6;
    int lane = gtid & 63;
    if (wid >= BATCH * CH) return;
    const float* src = fm + (size_t)wid * (HFD * HFD);
    float* dst = I + (size_t)wid * IRCP2;
    if (lane < IW) dst[lane] = 0.f;
    if (lane >= 1 && lane < IW) dst[lane * IW] = 0.f;
    int c = lane;
    float acc = 0.f;
    for (int r = 0; r < HFD; ++r) {
        float v = (c < HFD) ? src[r * HFD + c] : 0.f;
        #pragma unroll
        for (int d = 1; d < 32; d <<= 1) {
            float t = __shfl_up(v, d, 64);
            if (lane >= d) v += t;
        }
        acc += v;
        if (c < HFD) dst[(r + 1) * IW + (c + 1)] = acc;
    }
}

// ---------------- bias'[o] = L[o]·fc_b + {l_b|s_b}[o] ----------------------
__global__ void k_bias(const float* __restrict__ lw, const float* __restrict__ sw,
                       const float* __restrict__ fcb, const float* __restrict__ lb,
                       const float* __restrict__ sb, float* __restrict__ bias) {
    int o = blockIdx.x;
    __shared__ float red[256];
    float s = 0.f;
    if (o < NO) {
        const float* row = (o < 80) ? (lw + (size_t)o * FDIM) : (sw + (size_t)(o - 80) * FDIM);
        for (int f = threadIdx.x; f < FDIM; f += 256) s += row[f] * fcb[f];
    }
    red[threadIdx.x] = s;
    __syncthreads();
    for (int st = 128; st > 0; st >>= 1) {
        if ((int)threadIdx.x < st) red[threadIdx.x] += red[threadIdx.x + st];
        __syncthreads();
    }
    if (threadIdx.x == 0) {
        float bv = 0.f;
        if (o < 80) bv = red[0] + lb[o];
        else if (o < NO) bv = red[0] + sb[o - 80];
        bias[o] = bv;
    }
}

// ---------------- Wc partials via MFMA, 1-wave blocks, wave-k = 64 ---------
// Wcp[fs][k][o] = sum_{f in chunk fs} L[o][f] * W1[f][k]
// grid (392, 2), block = 64 threads (ONE wave). k-tile 64, f-chunk 2048
// (64 steps of 32f). ~3 independent waves/CU -> each wave's vmcnt drain at
// the step boundary overlaps other blocks' compute (m114), on EVERY CU.
// Tile [32f][64k] fp32 dbuf (16 KB), global_load_lds dwordx4, XOR swizzle
// on the GLOBAL source (LDS dest linear):
//   LDS (row, byte) holds W1[f0+row][k0 + ((byte ^ (((row>>3)&3)<<6))>>2)]
// Read applies same XOR -> 2 lanes/bank (free).
// (round-8 lesson: never reduce across blocks via dense atomics — stream
// partial slices + fused reduce.)
#define WC_STAGE(S, DB)                                                       \
  {                                                                           \
    const float* gb_ = W1                                                     \
        + (size_t)(fs * 2048 + (S) * 32 + (lane >> 4)) * KD + k0;             \
    _Pragma("unroll")                                                         \
    for (int i_ = 0; i_ < 8; ++i_) {                                          \
      unsigned sw_ = ((unsigned)((i_ >> 1) & 3)) << 6;                        \
      unsigned gc_ = (lin16 ^ sw_) >> 2;                                      \
      GLL16(gb_ + (size_t)(4 * i_) * KD + gc_, &Bs[DB][i_ * 256]);            \
    }                                                                         \
  }

#define WC_STEP(S, DB)                                                        \
  {                                                                           \
    u32v4 ah[MFRAG], am[MFRAG];                                               \
    _Pragma("unroll")                                                         \
    for (int mf = 0; mf < MFRAG; ++mf) {                                      \
      size_t ai = (size_t)((mf * 128 + fs * WCSTEPS + (S)) * 64 + lane);      \
      ah[mf] = Ahi[ai]; am[mf] = Amd[ai];                                     \
    }                                                                         \
    const char* bs_ = (const char*)&Bs[DB][0];                                \
    _Pragma("unroll")                                                         \
    for (int nf = 0; nf < 4; ++nf) {                                          \
      float bv[8];                                                            \
      _Pragma("unroll")                                                       \
      for (int j = 0; j < 8; ++j)                                             \
        bv[j] = *(const float*)(bs_ + (rowg * 8 + j) * 256 + kb[nf]);         \
      u32v4 bhw, bmw;                                                         \
      _Pragma("unroll")                                                       \
      for (int w_ = 0; w_ < 4; ++w_)                                          \
        SPLIT2T(bv[2 * w_], bv[2 * w_ + 1], bhw[w_], bmw[w_]);                \
      bf16x8 bh = __builtin_bit_cast(bf16x8, bhw);                            \
      bf16x8 bm = __builtin_bit_cast(bf16x8, bmw);                            \
      _Pragma("unroll")                                                       \
      for (int mf = 0; mf < MFRAG; ++mf) {                                    \
        bf16x8 a_h = __builtin_bit_cast(bf16x8, ah[mf]);                      \
        bf16x8 a_m = __builtin_bit_cast(bf16x8, am[mf]);                      \
        acc[mf][nf] = MFMA16(a_h, bh, acc[mf][nf], 0, 0, 0);                  \
        acc[mf][nf] = MFMA16(a_m, bh, acc[mf][nf], 0, 0, 0);                  \
        acc[mf][nf] = MFMA16(a_h, bm, acc[mf][nf], 0, 0, 0);                  \
      }                                                                       \
    }                                                                         \
  }

__global__ void __launch_bounds__(64, 2) k_wc(const float* __restrict__ W1,
                                              const u32v4* __restrict__ Ahi,
                                              const u32v4* __restrict__ Amd,
                                              float* __restrict__ Wcp) {
    __shared__ float Bs[2][32 * 64];   // 2 x 8 KB
    int lane = threadIdx.x;
    int kblk = blockIdx.x;             // 0..391
    int fs = blockIdx.y;               // 0..1
    int k0 = kblk * 64;
    int col = lane & 15, rowg = lane >> 4;
    unsigned lin16 = (unsigned)(lane & 15) * 16;

    unsigned kb[4];
    #pragma unroll
    for (int nf = 0; nf < 4; ++nf)
        kb[nf] = ((unsigned)((nf * 16 + col) * 4)) ^ ((unsigned)rowg << 6);

    f32x4 acc[MFRAG][4];
    #pragma unroll
    for (int mf = 0; mf < MFRAG; ++mf)
        #pragma unroll
        for (int nf = 0; nf < 4; ++nf)
            acc[mf][nf] = (f32x4){0.f, 0.f, 0.f, 0.f};

    WC_STAGE(0, 0);
    __syncthreads();
    for (int s = 0; s < WCSTEPS; ++s) {
        int db = s & 1;
        if (s + 1 < WCSTEPS) WC_STAGE(s + 1, db ^ 1);
        WC_STEP(s, db);
        __syncthreads();
    }

    float* wp = Wcp + (size_t)fs * S_WC;
    #pragma unroll
    for (int mf = 0; mf < MFRAG; ++mf)
        #pragma unroll
        for (int nf = 0; nf < 4; ++nf) {
            size_t k = (size_t)k0 + nf * 16 + col;
            int o = mf * 16 + (rowg << 2);
            *(f32x4*)(wp + k * OP2 + o) = acc[mf][nf];
        }
}

// ---------------- fused: reduce 2 f-chunks + 3-way split -> k_h A-tables ---
// Whi[((p*16+cs)*7+mf)*64 + lane] = 8 bf16 = Wc[c=cs*32+(l>>4)*8+j][o=mf*16+(l&15)]
__global__ void k_redsplit(const float* __restrict__ Wcp, u32v4* __restrict__ Whi,
                           u32v4* __restrict__ Wmd, u32v4* __restrict__ Wlo) {
    int t = blockIdx.x * 256 + threadIdx.x;   // over NFRAG_H*64
    int lane = t & 63;
    int fi = t >> 6;
    int p = fi / (16 * MFRAG);
    int rem = fi - p * (16 * MFRAG);
    int cs = rem / MFRAG, mf = rem - cs * MFRAG;
    int o = mf * 16 + (lane & 15);
    int c0 = cs * 32 + (lane >> 4) * 8;
    float v[8];
    #pragma unroll
    for (int j = 0; j < 8; ++j) {
        size_t base = ((size_t)(c0 + j) * NP + p) * OP2 + o;
        float s = 0.f;
        #pragma unroll
        for (int i = 0; i < FSPLIT; ++i) s += Wcp[base + (size_t)i * S_WC];
        v[j] = s;
    }
    u32v4 hw, mw, lww;
    #pragma unroll
    for (int w = 0; w < 4; ++w)
        SPLIT3PK(v[2 * w], v[2 * w + 1], hw[w], mw[w], lww[w]);
    Whi[(size_t)fi * 64 + lane] = hw;
    Wmd[(size_t)fi * 64 + lane] = mw;
    Wlo[(size_t)fi * 64 + lane] = lww;
}

// ---------------- H[b][p][rc][o] = sum_c Wc[c*49+p][o] * I[b][c][rc] -------
// MFMA, 6-product (H feeds corner-difference cancellation -> need ~2^-24 rel).
#define KH_STEP(CUR, NXT, S)                                                  \
  {                                                                           \
    if ((S) + 1 < 16) {                                                       \
      _Pragma("unroll")                                                       \
      for (int nf = 0; nf < 2; ++nf)                                          \
        _Pragma("unroll")                                                     \
        for (int j = 0; j < 8; ++j)                                           \
          NXT[nf][j] = Ib[(size_t)(((S) + 1) * 32 + rowg * 8 + j) * IRCP2 + nf * 16]; \
    }                                                                         \
    bf16x8 bh[2], bm[2], bl[2];                                               \
    _Pragma("unroll")                                                         \
    for (int nf = 0; nf < 2; ++nf) {                                          \
      u32v4 bhw, bmw, blw;                                                    \
      _Pragma("unroll")                                                       \
      for (int w_ = 0; w_ < 4; ++w_)                                          \
        SPLIT3PK(CUR[nf][2 * w_], CUR[nf][2 * w_ + 1], bhw[w_], bmw[w_], blw[w_]); \
      bh[nf] = __builtin_bit_cast(bf16x8, bhw);                               \
      bm[nf] = __builtin_bit_cast(bf16x8, bmw);                               \
      bl[nf] = __builtin_bit_cast(bf16x8, blw);                               \
    }                                                                         \
    _Pragma("unroll")                                                         \
    for (int mf = 0; mf < MFRAG; ++mf) {                                      \
      size_t ai = (size_t)(((p * 16 + (S)) * MFRAG + mf) * 64 + lane);        \
      bf16x8 a_h = __builtin_bit_cast(bf16x8, Whi[ai]);                       \
      bf16x8 a_m = __builtin_bit_cast(bf16x8, Wmd[ai]);                       \
      bf16x8 a_l = __builtin_bit_cast(bf16x8, Wlo[ai]);                       \
      _Pragma("unroll")                                                       \
      for (int nf = 0; nf < 2; ++nf) {                                        \
        acc[mf][nf] = MFMA16(a_h, bh[nf], acc[mf][nf], 0, 0, 0);              \
        acc[mf][nf] = MFMA16(a_m, bh[nf], acc[mf][nf], 0, 0, 0);              \
        acc[mf][nf] = MFMA16(a_h, bm[nf], acc[mf][nf], 0, 0, 0);              \
        acc[mf][nf] = MFMA16(a_m, bm[nf], acc[mf][nf], 0, 0, 0);              \
        acc[mf][nf] = MFMA16(a_l, bh[nf], acc[mf][nf], 0, 0, 0);              \
        acc[mf][nf] = MFMA16(a_h, bl[nf], acc[mf][nf], 0, 0, 0);              \
      }                                                                       \
    }                                                                         \
  }

__global__ void __launch_bounds__(256, 2) k_h(const float* __restrict__ I,
                                              const u32v4* __restrict__ Whi,
                                              const u32v4* __restrict__ Wmd,
                                              const u32v4* __restrict__ Wlo,
                                              float* __restrict__ H) {
    int lane = threadIdx.x & 63;
    int w = threadIdx.x >> 6;
    int rcb = blockIdx.x, p = blockIdx.y, b = blockIdx.z;
    int col = lane & 15, rowg = lane >> 4;
    int rcw = rcb * 128 + w * 32;                 // wave's rc base
    const float* Ib = I + (size_t)b * CH * IRCP2 + rcw + col;

    f32x4 acc[MFRAG][2];
    #pragma unroll
    for (int mf = 0; mf < MFRAG; ++mf) {
        acc[mf][0] = (f32x4){0.f, 0.f, 0.f, 0.f};
        acc[mf][1] = (f32x4){0.f, 0.f, 0.f, 0.f};
    }
    float ib0[2][8], ib1[2][8];
    #pragma unroll
    for (int nf = 0; nf < 2; ++nf)
        #pragma unroll
        for (int j = 0; j < 8; ++j)
            ib0[nf][j] = Ib[(size_t)(rowg * 8 + j) * IRCP2 + nf * 16];

    for (int s = 0; s < 16; s += 2) {
        KH_STEP(ib0, ib1, s);
        KH_STEP(ib1, ib0, s + 1);
    }

    #pragma unroll
    for (int mf = 0; mf < MFRAG; ++mf)
        #pragma unroll
        for (int nf = 0; nf < 2; ++nf) {
            int rc = rcw + nf * 16 + col;
            if (rc < IRC) {
                float* hp = H + (((size_t)(b * NP + p)) * IRC + rc) * OP2
                            + mf * 16 + rowg * 4;
                *(f32x4*)hp = acc[mf][nf];
            }
        }
}

// ---------------- per-box gather + bias + argmax + outputs -----------------
// 512 threads: o = t&127 (o<101 active), p-quarter = t>>7 -> 4-way LDS reduce.
__global__ void __launch_bounds__(512) k_out(const float* __restrict__ boxes,
                                             const float* __restrict__ H,
                                             const float* __restrict__ bias,
                                             float* __restrict__ out) {
    int n = blockIdx.x, b = blockIdx.y;
    int t = threadIdx.x;
    __shared__ int srs[PPOOL], sre[PPOOL], scs[PPOOL], sce[PPOOL];
    __shared__ float sinv[NP];
    __shared__ float psum[4][NO];
    __shared__ float sl[NO];
    __shared__ int smi;
    const float* bx = boxes + ((size_t)b * NBOX + n) * 4;
    if (t < PPOOL) {
        int r0 = (int)(bx[0] / 32.0f);
        int c0 = (int)(bx[1] / 32.0f);
        int r1 = (int)(bx[2] / 32.0f);
        int c1 = (int)(bx[3] / 32.0f);
        int sr = r1 - r0, sc = c1 - c0;
        srs[t] = r0 + (t * sr) / PPOOL;
        sre[t] = r0 + ((t + 1) * sr + PPOOL - 1) / PPOOL;
        scs[t] = c0 + (t * sc) / PPOOL;
        sce[t] = c0 + ((t + 1) * sc + PPOOL - 1) / PPOOL;
    }
    __syncthreads();
    if (t < NP) {
        int ph = t / PPOOL, pw = t - ph * PPOOL;
        sinv[t] = 1.0f / (float)((sre[ph] - srs[ph]) * (sce[pw] - scs[pw]));
    }
    __syncthreads();
    int o = t & 127, q = t >> 7;
    if (o < NO) {
        int p0 = q ? (12 * q + 1) : 0;       // {0,13,25,37}
        int p1 = 12 * q + 13;                // {13,25,37,49}
        float acc = 0.f;
        const float* Hb = H + (size_t)b * NP * IRC * OP2 + o;
        for (int p = p0; p < p1; ++p) {
            int ph = p / PPOOL, pw = p - ph * PPOOL;
            const float* Hp = Hb + (size_t)p * IRC * OP2;
            int re = sre[ph], rs = srs[ph], ce = sce[pw], cs = scs[pw];
            float v = Hp[(size_t)(re * IW + ce) * OP2] - Hp[(size_t)(rs * IW + ce) * OP2]
                    - Hp[(size_t)(re * IW + cs) * OP2] + Hp[(size_t)(rs * IW + cs) * OP2];
            acc += v * sinv[p];
        }
        psum[q][o] = acc;
    }
    __syncthreads();
    if (t < NO) {
        float v = psum[0][t] + psum[1][t] + psum[2][t] + psum[3][t] + bias[t];
        sl[t] = v;
        if (t >= 80)
            out[(size_t)(4 * BATCH * NBOX) + ((size_t)b * NBOX + n) * (NCLS + 1) + (t - 80)] = v;
    }
    __syncthreads();
    if (t == 0) {
        float best = sl[80]; int mi = 0;
        for (int s = 1; s <= NCLS; ++s) {
            float v = sl[80 + s];
            if (v > best) { best = v; mi = s; }
        }
        smi = mi;
    }
    __syncthreads();
    if (t < 4) out[((size_t)b * NBOX + n) * 4 + t] = sl[smi + t];
}

extern "C" void kernel_launch(void* const* d_in, const int* in_sizes, int n_in,
                              void* d_out, int out_size, void* d_ws, size_t ws_size,
                              hipStream_t stream) {
    const float* fm    = (const float*)d_in[0];
    const float* boxes = (const float*)d_in[1];
    const float* fcw   = (const float*)d_in[2];
    const float* fcb   = (const float*)d_in[3];
    const float* lw    = (const float*)d_in[4];
    const float* lb    = (const float*)d_in[5];
    const float* sw    = (const float*)d_in[6];
    const float* sb    = (const float*)d_in[7];
    float* out = (float*)d_out;

    float* ws = (float*)d_ws;
    float* I    = ws;                                        // 786,432 f
    u32v4* Ahi  = (u32v4*)(I + (size_t)BATCH * CH * IRCP2);  // 57,344 frag-words
    u32v4* Amd  = Ahi + MFRAG * NSTEP_TOT * 64;
    float* bias = (float*)(Amd + MFRAG * NSTEP_TOT * 64);    // 128 f
    float* Wcp  = bias + 128;                                // 2 * S_WC f (22.5 MB)
    u32v4* Whi  = (u32v4*)(Wcp + (size_t)FSPLIT * S_WC);     // 351,232 frag-words
    u32v4* Wmd  = Whi + (size_t)NFRAG_H * 64;
    u32v4* Wlo  = Wmd + (size_t)NFRAG_H * 64;
    float* H    = (float*)(Wlo + (size_t)NFRAG_H * 64);      // 7,419,392 f
    // total ws ~= 75 MB

    hipLaunchKernelGGL(k_lt, dim3(224), dim3(256), 0, stream, lw, sw, Ahi, Amd);
    hipLaunchKernelGGL(k_integral, dim3(256), dim3(256), 0, stream, fm, I);
    hipLaunchKernelGGL(k_bias, dim3(104), dim3(256), 0, stream, lw, sw, fcb, lb, sb, bias);
    hipLaunchKernelGGL(k_wc, dim3(392, FSPLIT), dim3(64), 0, stream, fcw, Ahi, Amd, Wcp);
    hipLaunchKernelGGL(k_redsplit, dim3(NFRAG_H * 64 / 256), dim3(256), 0, stream, Wcp, Whi, Wmd, Wlo);
    hipLaunchKernelGGL(k_h, dim3(6, NP, BATCH), dim3(256), 0, stream, I, Whi, Wmd, Wlo, H);
    hipLaunchKernelGGL(k_out, dim3(NBOX, BATCH), dim3(512), 0, stream, boxes, H, bias, out);
}

// Round 12
// 224.862 us; speedup vs baseline: 1.0772x; 1.0772x over previous
//
#include <hip/hip_runtime.h>

#define BATCH 2
#define NBOX 500
#define CH 512
#define HFD 25
#define IW 26
#define IRC 676            // 26*26
#define IRCP2 768          // padded channel stride (covers rc-tile overreach)
#define PPOOL 7
#define NP 49
#define NCLS 20
#define NO 101             // 80 loc + 21 score
#define OP2 112            // o padded to 7*16
#define MFRAG 7
#define KD 25088
#define FDIM 4096
#define NSTEP_TOT 128      // FDIM/32
#define FSPLIT 5           // 98*5 = 490 blocks ~ 512 CU-slots (4% tail waste vs 23%)
#define S_WC ((size_t)KD * OP2)   // 2,809,856
#define NFRAG_H (NP * 16 * MFRAG) // 5488 fragments per table for k_h

typedef __attribute__((ext_vector_type(4))) float f32x4;
typedef __attribute__((ext_vector_type(8))) short bf16x8;
typedef __attribute__((ext_vector_type(4))) unsigned int u32v4;

#define MFMA16 __builtin_amdgcn_mfma_f32_16x16x32_bf16

typedef __attribute__((address_space(1))) const unsigned int guint;
typedef __attribute__((address_space(3))) unsigned int luint;
#define GLL16(G, L) __builtin_amdgcn_global_load_lds((guint*)(G), (luint*)(L), 16, 0, 0)

// ---- 2-way split of an fp32 pair: hi = trunc-bf16(v), mid = RN-bf16(v-hi).
#define SPLIT2PK(V0, V1, HW, MW)                                       \
  {                                                                    \
    unsigned u0_ = __float_as_uint(V0), u1_ = __float_as_uint(V1);     \
    HW = (u0_ >> 16) | (u1_ & 0xffff0000u);                            \
    float r0_ = (V0) - __uint_as_float(u0_ & 0xffff0000u);             \
    float r1_ = (V1) - __uint_as_float(u1_ & 0xffff0000u);             \
    unsigned m0_ = __float_as_uint(r0_), m1_ = __float_as_uint(r1_);   \
    m0_ += 0x7fffu + ((m0_ >> 16) & 1u);                               \
    m1_ += 0x7fffu + ((m1_ >> 16) & 1u);                               \
    MW = (m0_ >> 16) | (m1_ & 0xffff0000u);                            \
  }

// ---- cheap variant: hi trunc, mid = trunc-bf16(v-hi); |rho| <= 2^-16|v| ----
#define SPLIT2T(V0, V1, HW, MW)                                        \
  {                                                                    \
    unsigned u0_ = __float_as_uint(V0), u1_ = __float_as_uint(V1);     \
    HW = (u0_ >> 16) | (u1_ & 0xffff0000u);                            \
    float r0_ = (V0) - __uint_as_float(u0_ & 0xffff0000u);             \
    float r1_ = (V1) - __uint_as_float(u1_ & 0xffff0000u);             \
    MW = (__float_as_uint(r0_) >> 16) |                                \
         (__float_as_uint(r1_) & 0xffff0000u);                         \
  }

// ---- exact 3-way truncation split (24-bit mantissa = 8+8+8) ----
#define SPLIT3PK(V0, V1, HW, MW, LW)                                   \
  {                                                                    \
    unsigned u0_ = __float_as_uint(V0), u1_ = __float_as_uint(V1);     \
    HW = (u0_ >> 16) | (u1_ & 0xffff0000u);                            \
    float r0_ = (V0) - __uint_as_float(u0_ & 0xffff0000u);             \
    float r1_ = (V1) - __uint_as_float(u1_ & 0xffff0000u);             \
    unsigned m0_ = __float_as_uint(r0_), m1_ = __float_as_uint(r1_);   \
    MW = (m0_ >> 16) | (m1_ & 0xffff0000u);                            \
    float s0_ = r0_ - __uint_as_float(m0_ & 0xffff0000u);              \
    float s1_ = r1_ - __uint_as_float(m1_ & 0xffff0000u);              \
    LW = (__float_as_uint(s0_) >> 16) |                                \
         (__float_as_uint(s1_) & 0xffff0000u);                         \
  }

// ---------------- A-tables: L=[l_w;s_w] -> MFMA A-frags, 2-way split -------
// Ahi[(mf*128 + s)*64 + lane] = 8 bf16 = A[o=mf*16+(l&15)][f=s*32+(l>>4)*8+j]
__global__ void k_lt(const float* __restrict__ lw, const float* __restrict__ sw,
                     u32v4* __restrict__ Ahi, u32v4* __restrict__ Amd) {
    int t = blockIdx.x * 256 + threadIdx.x;
    if (t >= MFRAG * NSTEP_TOT * 64) return;
    int lane = t & 63;
    int wv = t >> 6;                 // (mf*128 + s)
    int s = wv & 127, mf = wv >> 7;
    int o = mf * 16 + (lane & 15);
    int f0 = s * 32 + (lane >> 4) * 8;
    float v[8];
    const float* row = nullptr;
    if (o < 80) row = lw + (size_t)o * FDIM;
    else if (o < NO) row = sw + (size_t)(o - 80) * FDIM;
    #pragma unroll
    for (int j = 0; j < 8; ++j) v[j] = row ? row[f0 + j] : 0.f;
    u32v4 hw, mw;
    #pragma unroll
    for (int w = 0; w < 4; ++w)
        SPLIT2PK(v[2 * w], v[2 * w + 1], hw[w], mw[w]);
    Ahi[(size_t)wv * 64 + lane] = hw;
    Amd[(size_t)wv * 64 + lane] = mw;
}

// ---------------- integral image, c-major, padded stride 768 ---------------
__global__ void k_integral(const float* __restrict__ fm, float* __restrict__ I) {
    int gtid = blockIdx.x * blockDim.x + threadIdx.x;
    int wid = gtid >> 6;
    int lane = gtid & 63;
    if (wid >= BATCH * CH) return;
    const float* src = fm + (size_t)wid * (HFD * HFD);
    float* dst = I + (size_t)wid * IRCP2;
    if (lane < IW) dst[lane] = 0.f;
    if (lane >= 1 && lane < IW) dst[lane * IW] = 0.f;
    int c = lane;
    float acc = 0.f;
    for (int r = 0; r < HFD; ++r) {
        float v = (c < HFD) ? src[r * HFD + c] : 0.f;
        #pragma unroll
        for (int d = 1; d < 32; d <<= 1) {
            float t = __shfl_up(v, d, 64);
            if (lane >= d) v += t;
        }
        acc += v;
        if (c < HFD) dst[(r + 1) * IW + (c + 1)] = acc;
    }
}

// ---------------- bias'[o] = L[o]·fc_b + {l_b|s_b}[o] ----------------------
__global__ void k_bias(const float* __restrict__ lw, const float* __restrict__ sw,
                       const float* __restrict__ fcb, const float* __restrict__ lb,
                       const float* __restrict__ sb, float* __restrict__ bias) {
    int o = blockIdx.x;
    __shared__ float red[256];
    float s = 0.f;
    if (o < NO) {
        const float* row = (o < 80) ? (lw + (size_t)o * FDIM) : (sw + (size_t)(o - 80) * FDIM);
        for (int f = threadIdx.x; f < FDIM; f += 256) s += row[f] * fcb[f];
    }
    red[threadIdx.x] = s;
    __syncthreads();
    for (int st = 128; st > 0; st >>= 1) {
        if ((int)threadIdx.x < st) red[threadIdx.x] += red[threadIdx.x + st];
        __syncthreads();
    }
    if (threadIdx.x == 0) {
        float bv = 0.f;
        if (o < 80) bv = red[0] + lb[o];
        else if (o < NO) bv = red[0] + sb[o - 80];
        bias[o] = bv;
    }
}

// ---------------- Wc partials via MFMA, LDS-staged, wave-k = 64 ------------
// Wcp[fs][k][o] = sum_{f in chunk fs} L[o][f] * W1[f][k]
// grid (98, 5): x = k-block (256 k), y = f-chunk. 4 waves, 2 blocks/CU (LDS),
// 490 blocks ~ 512 slots -> balanced critical path (round-9's 392 left 120
// CUs idle for half the kernel; round-11's 1-wave variant cut TLP — both
// reverted). Chunk fs covers global steps [(fs*128)/5, ((fs+1)*128)/5).
// Tile [32f][256k] fp32 dbuf, global_load_lds dwordx4, XOR swizzle on the
// GLOBAL source (LDS dest linear):
//   LDS (row, kbyte) holds W1[f0+row][k0 + ((kbyte ^ (((row>>3)&3)<<6))>>2)]
// (round-8 lesson: never cross-block-reduce via dense atomics.)
#define WC_STAGE(G, DB)                                                       \
  {                                                                           \
    const float* gb_ = W1 + (size_t)((G) * 32 + w) * KD + k0;                 \
    _Pragma("unroll")                                                         \
    for (int i_ = 0; i_ < 8; ++i_) {                                          \
      unsigned gc_ = (lb16 ^ ((unsigned)(i_ >> 1) << 6)) >> 2;                \
      GLL16(gb_ + (size_t)(4 * i_) * KD + gc_,                                \
            &Bs[DB][i_ * 1024 + w * 256]);                                    \
    }                                                                         \
  }

#define WC_STEP(G, DB)                                                        \
  {                                                                           \
    u32v4 ah[MFRAG], am[MFRAG];                                               \
    _Pragma("unroll")                                                         \
    for (int mf = 0; mf < MFRAG; ++mf) {                                      \
      size_t ai = (size_t)((mf * 128 + (G)) * 64 + lane);                     \
      ah[mf] = Ahi[ai]; am[mf] = Amd[ai];                                     \
    }                                                                         \
    const char* bs_ = (const char*)&Bs[DB][0];                                \
    _Pragma("unroll")                                                         \
    for (int nf = 0; nf < 4; ++nf) {                                          \
      float bv[8];                                                            \
      _Pragma("unroll")                                                       \
      for (int j = 0; j < 8; ++j)                                             \
        bv[j] = *(const float*)(bs_ + (rowg * 8 + j) * 1024 + kb[nf]);        \
      u32v4 bhw, bmw;                                                         \
      _Pragma("unroll")                                                       \
      for (int w_ = 0; w_ < 4; ++w_)                                          \
        SPLIT2T(bv[2 * w_], bv[2 * w_ + 1], bhw[w_], bmw[w_]);                \
      bf16x8 bh = __builtin_bit_cast(bf16x8, bhw);                            \
      bf16x8 bm = __builtin_bit_cast(bf16x8, bmw);                            \
      _Pragma("unroll")                                                       \
      for (int mf = 0; mf < MFRAG; ++mf) {                                    \
        bf16x8 a_h = __builtin_bit_cast(bf16x8, ah[mf]);                      \
        bf16x8 a_m = __builtin_bit_cast(bf16x8, am[mf]);                      \
        acc[mf][nf] = MFMA16(a_h, bh, acc[mf][nf], 0, 0, 0);                  \
        acc[mf][nf] = MFMA16(a_m, bh, acc[mf][nf], 0, 0, 0);                  \
        acc[mf][nf] = MFMA16(a_h, bm, acc[mf][nf], 0, 0, 0);                  \
      }                                                                       \
    }                                                                         \
  }

__global__ void __launch_bounds__(256, 2) k_wc(const float* __restrict__ W1,
                                               const u32v4* __restrict__ Ahi,
                                               const u32v4* __restrict__ Amd,
                                               float* __restrict__ Wcp) {
    __shared__ float Bs[2][32 * 256];
    int lane = threadIdx.x & 63;
    int w = threadIdx.x >> 6;        // wave 0..3
    int kblk = blockIdx.x;           // 0..97
    int fs = blockIdx.y;             // 0..4
    int k0 = kblk * 256;
    int col = lane & 15, rowg = lane >> 4;
    unsigned lb16 = (unsigned)lane * 16;

    int gstart = (fs * NSTEP_TOT) / FSPLIT;
    int gend = ((fs + 1) * NSTEP_TOT) / FSPLIT;

    unsigned kb[4];
    #pragma unroll
    for (int nf = 0; nf < 4; ++nf)
        kb[nf] = ((unsigned)((w * 64 + nf * 16 + col) * 4)) ^ ((unsigned)rowg << 6);

    f32x4 acc[MFRAG][4];
    #pragma unroll
    for (int mf = 0; mf < MFRAG; ++mf)
        #pragma unroll
        for (int nf = 0; nf < 4; ++nf)
            acc[mf][nf] = (f32x4){0.f, 0.f, 0.f, 0.f};

    WC_STAGE(gstart, 0);
    __syncthreads();
    for (int g = gstart; g < gend; ++g) {
        int db = (g - gstart) & 1;
        if (g + 1 < gend) WC_STAGE(g + 1, db ^ 1);
        WC_STEP(g, db);
        __syncthreads();
    }

    float* wp = Wcp + (size_t)fs * S_WC;
    #pragma unroll
    for (int mf = 0; mf < MFRAG; ++mf)
        #pragma unroll
        for (int nf = 0; nf < 4; ++nf) {
            size_t k = (size_t)k0 + w * 64 + nf * 16 + col;
            int o = mf * 16 + (rowg << 2);
            *(f32x4*)(wp + k * OP2 + o) = acc[mf][nf];
        }
}

// ---------------- fused: reduce 5 f-chunks + 3-way split -> k_h A-tables ---
// Whi[((p*16+cs)*7+mf)*64 + lane] = 8 bf16 = Wc[c=cs*32+(l>>4)*8+j][o=mf*16+(l&15)]
__global__ void k_redsplit(const float* __restrict__ Wcp, u32v4* __restrict__ Whi,
                           u32v4* __restrict__ Wmd, u32v4* __restrict__ Wlo) {
    int t = blockIdx.x * 256 + threadIdx.x;   // over NFRAG_H*64
    int lane = t & 63;
    int fi = t >> 6;
    int p = fi / (16 * MFRAG);
    int rem = fi - p * (16 * MFRAG);
    int cs = rem / MFRAG, mf = rem - cs * MFRAG;
    int o = mf * 16 + (lane & 15);
    int c0 = cs * 32 + (lane >> 4) * 8;
    float v[8];
    #pragma unroll
    for (int j = 0; j < 8; ++j) {
        size_t base = ((size_t)(c0 + j) * NP + p) * OP2 + o;
        float s = 0.f;
        #pragma unroll
        for (int i = 0; i < FSPLIT; ++i) s += Wcp[base + (size_t)i * S_WC];
        v[j] = s;
    }
    u32v4 hw, mw, lww;
    #pragma unroll
    for (int w = 0; w < 4; ++w)
        SPLIT3PK(v[2 * w], v[2 * w + 1], hw[w], mw[w], lww[w]);
    Whi[(size_t)fi * 64 + lane] = hw;
    Wmd[(size_t)fi * 64 + lane] = mw;
    Wlo[(size_t)fi * 64 + lane] = lww;
}

// ---------------- H[b][p][rc][o] = sum_c Wc[c*49+p][o] * I[b][c][rc] -------
// MFMA, 6-product (H feeds corner-difference cancellation -> need ~2^-24 rel).
#define KH_STEP(CUR, NXT, S)                                                  \
  {                                                                           \
    if ((S) + 1 < 16) {                                                       \
      _Pragma("unroll")                                                       \
      for (int nf = 0; nf < 2; ++nf)                                          \
        _Pragma("unroll")                                                     \
        for (int j = 0; j < 8; ++j)                                           \
          NXT[nf][j] = Ib[(size_t)(((S) + 1) * 32 + rowg * 8 + j) * IRCP2 + nf * 16]; \
    }                                                                         \
    bf16x8 bh[2], bm[2], bl[2];                                               \
    _Pragma("unroll")                                                         \
    for (int nf = 0; nf < 2; ++nf) {                                          \
      u32v4 bhw, bmw, blw;                                                    \
      _Pragma("unroll")                                                       \
      for (int w_ = 0; w_ < 4; ++w_)                                          \
        SPLIT3PK(CUR[nf][2 * w_], CUR[nf][2 * w_ + 1], bhw[w_], bmw[w_], blw[w_]); \
      bh[nf] = __builtin_bit_cast(bf16x8, bhw);                               \
      bm[nf] = __builtin_bit_cast(bf16x8, bmw);                               \
      bl[nf] = __builtin_bit_cast(bf16x8, blw);                               \
    }                                                                         \
    _Pragma("unroll")                                                         \
    for (int mf = 0; mf < MFRAG; ++mf) {                                      \
      size_t ai = (size_t)(((p * 16 + (S)) * MFRAG + mf) * 64 + lane);        \
      bf16x8 a_h = __builtin_bit_cast(bf16x8, Whi[ai]);                       \
      bf16x8 a_m = __builtin_bit_cast(bf16x8, Wmd[ai]);                       \
      bf16x8 a_l = __builtin_bit_cast(bf16x8, Wlo[ai]);                       \
      _Pragma("unroll")                                                       \
      for (int nf = 0; nf < 2; ++nf) {                                        \
        acc[mf][nf] = MFMA16(a_h, bh[nf], acc[mf][nf], 0, 0, 0);              \
        acc[mf][nf] = MFMA16(a_m, bh[nf], acc[mf][nf], 0, 0, 0);              \
        acc[mf][nf] = MFMA16(a_h, bm[nf], acc[mf][nf], 0, 0, 0);              \
        acc[mf][nf] = MFMA16(a_m, bm[nf], acc[mf][nf], 0, 0, 0);              \
        acc[mf][nf] = MFMA16(a_l, bh[nf], acc[mf][nf], 0, 0, 0);              \
        acc[mf][nf] = MFMA16(a_h, bl[nf], acc[mf][nf], 0, 0, 0);              \
      }                                                                       \
    }                                                                         \
  }

__global__ void __launch_bounds__(256, 2) k_h(const float* __restrict__ I,
                                              const u32v4* __restrict__ Whi,
                                              const u32v4* __restrict__ Wmd,
                                              const u32v4* __restrict__ Wlo,
                                              float* __restrict__ H) {
    int lane = threadIdx.x & 63;
    int w = threadIdx.x >> 6;
    int rcb = blockIdx.x, p = blockIdx.y, b = blockIdx.z;
    int col = lane & 15, rowg = lane >> 4;
    int rcw = rcb * 128 + w * 32;                 // wave's rc base
    const float* Ib = I + (size_t)b * CH * IRCP2 + rcw + col;

    f32x4 acc[MFRAG][2];
    #pragma unroll
    for (int mf = 0; mf < MFRAG; ++mf) {
        acc[mf][0] = (f32x4){0.f, 0.f, 0.f, 0.f};
        acc[mf][1] = (f32x4){0.f, 0.f, 0.f, 0.f};
    }
    float ib0[2][8], ib1[2][8];
    #pragma unroll
    for (int nf = 0; nf < 2; ++nf)
        #pragma unroll
        for (int j = 0; j < 8; ++j)
            ib0[nf][j] = Ib[(size_t)(rowg * 8 + j) * IRCP2 + nf * 16];

    for (int s = 0; s < 16; s += 2) {
        KH_STEP(ib0, ib1, s);
        KH_STEP(ib1, ib0, s + 1);
    }

    #pragma unroll
    for (int mf = 0; mf < MFRAG; ++mf)
        #pragma unroll
        for (int nf = 0; nf < 2; ++nf) {
            int rc = rcw + nf * 16 + col;
            if (rc < IRC) {
                float* hp = H + (((size_t)(b * NP + p)) * IRC + rc) * OP2
                            + mf * 16 + rowg * 4;
                *(f32x4*)hp = acc[mf][nf];
            }
        }
}

// ---------------- per-box gather + bias + argmax + outputs -----------------
// 512 threads: o = t&127 (o<101 active), p-quarter = t>>7 -> 4-way LDS reduce.
__global__ void __launch_bounds__(512) k_out(const float* __restrict__ boxes,
                                             const float* __restrict__ H,
                                             const float* __restrict__ bias,
                                             float* __restrict__ out) {
    int n = blockIdx.x, b = blockIdx.y;
    int t = threadIdx.x;
    __shared__ int srs[PPOOL], sre[PPOOL], scs[PPOOL], sce[PPOOL];
    __shared__ float sinv[NP];
    __shared__ float psum[4][NO];
    __shared__ float sl[NO];
    __shared__ int smi;
    const float* bx = boxes + ((size_t)b * NBOX + n) * 4;
    if (t < PPOOL) {
        int r0 = (int)(bx[0] / 32.0f);
        int c0 = (int)(bx[1] / 32.0f);
        int r1 = (int)(bx[2] / 32.0f);
        int c1 = (int)(bx[3] / 32.0f);
        int sr = r1 - r0, sc = c1 - c0;
        srs[t] = r0 + (t * sr) / PPOOL;
        sre[t] = r0 + ((t + 1) * sr + PPOOL - 1) / PPOOL;
        scs[t] = c0 + (t * sc) / PPOOL;
        sce[t] = c0 + ((t + 1) * sc + PPOOL - 1) / PPOOL;
    }
    __syncthreads();
    if (t < NP) {
        int ph = t / PPOOL, pw = t - ph * PPOOL;
        sinv[t] = 1.0f / (float)((sre[ph] - srs[ph]) * (sce[pw] - scs[pw]));
    }
    __syncthreads();
    int o = t & 127, q = t >> 7;
    if (o < NO) {
        int p0 = q ? (12 * q + 1) : 0;       // {0,13,25,37}
        int p1 = 12 * q + 13;                // {13,25,37,49}
        float acc = 0.f;
        const float* Hb = H + (size_t)b * NP * IRC * OP2 + o;
        for (int p = p0; p < p1; ++p) {
            int ph = p / PPOOL, pw = p - ph * PPOOL;
            const float* Hp = Hb + (size_t)p * IRC * OP2;
            int re = sre[ph], rs = srs[ph], ce = sce[pw], cs = scs[pw];
            float v = Hp[(size_t)(re * IW + ce) * OP2] - Hp[(size_t)(rs * IW + ce) * OP2]
                    - Hp[(size_t)(re * IW + cs) * OP2] + Hp[(size_t)(rs * IW + cs) * OP2];
            acc += v * sinv[p];
        }
        psum[q][o] = acc;
    }
    __syncthreads();
    if (t < NO) {
        float v = psum[0][t] + psum[1][t] + psum[2][t] + psum[3][t] + bias[t];
        sl[t] = v;
        if (t >= 80)
            out[(size_t)(4 * BATCH * NBOX) + ((size_t)b * NBOX + n) * (NCLS + 1) + (t - 80)] = v;
    }
    __syncthreads();
    if (t == 0) {
        float best = sl[80]; int mi = 0;
        for (int s = 1; s <= NCLS; ++s) {
            float v = sl[80 + s];
            if (v > best) { best = v; mi = s; }
        }
        smi = mi;
    }
    __syncthreads();
    if (t < 4) out[((size_t)b * NBOX + n) * 4 + t] = sl[smi + t];
}

extern "C" void kernel_launch(void* const* d_in, const int* in_sizes, int n_in,
                              void* d_out, int out_size, void* d_ws, size_t ws_size,
                              hipStream_t stream) {
    const float* fm    = (const float*)d_in[0];
    const float* boxes = (const float*)d_in[1];
    const float* fcw   = (const float*)d_in[2];
    const float* fcb   = (const float*)d_in[3];
    const float* lw    = (const float*)d_in[4];
    const float* lb    = (const float*)d_in[5];
    const float* sw    = (const float*)d_in[6];
    const float* sb    = (const float*)d_in[7];
    float* out = (float*)d_out;

    float* ws = (float*)d_ws;
    float* I    = ws;                                        // 786,432 f
    u32v4* Ahi  = (u32v4*)(I + (size_t)BATCH * CH * IRCP2);  // 57,344 frag-words
    u32v4* Amd  = Ahi + MFRAG * NSTEP_TOT * 64;
    float* bias = (float*)(Amd + MFRAG * NSTEP_TOT * 64);    // 128 f
    float* Wcp  = bias + 128;                                // 5 * S_WC f (56 MB)
    u32v4* Whi  = (u32v4*)(Wcp + (size_t)FSPLIT * S_WC);     // 351,232 frag-words
    u32v4* Wmd  = Whi + (size_t)NFRAG_H * 64;
    u32v4* Wlo  = Wmd + (size_t)NFRAG_H * 64;
    float* H    = (float*)(Wlo + (size_t)NFRAG_H * 64);      // 7,419,392 f
    // total ws ~= 108 MB

    hipLaunchKernelGGL(k_lt, dim3(224), dim3(256), 0, stream, lw, sw, Ahi, Amd);
    hipLaunchKernelGGL(k_integral, dim3(256), dim3(256), 0, stream, fm, I);
    hipLaunchKernelGGL(k_bias, dim3(104), dim3(256), 0, stream, lw, sw, fcb, lb, sb, bias);
    hipLaunchKernelGGL(k_wc, dim3(98, FSPLIT), dim3(256), 0, stream, fcw, Ahi, Amd, Wcp);
    hipLaunchKernelGGL(k_redsplit, dim3(NFRAG_H * 64 / 256), dim3(256), 0, stream, Wcp, Whi, Wmd, Wlo);
    hipLaunchKernelGGL(k_h, dim3(6, NP, BATCH), dim3(256), 0, stream, I, Whi, Wmd, Wlo, H);
    hipLaunchKernelGGL(k_out, dim3(NBOX, BATCH), dim3(512), 0, stream, boxes, H, bias, out);
}

// Round 13
// 224.859 us; speedup vs baseline: 1.0772x; 1.0000x over previous
//
#include <hip/hip_runtime.h>

#define BATCH 2
#define NBOX 500
#define CH 512
#define HFD 25
#define IW 26
#define IRC 676            // 26*26
#define IRCP2 768          // padded channel stride (covers rc-tile overreach)
#define PPOOL 7
#define NP 49
#define NCLS 20
#define NO 101             // 80 loc + 21 score
#define OP2 112            // o padded to 7*16
#define MFRAG 7
#define KD 25088
#define FDIM 4096
#define NSTEP_TOT 128      // FDIM/32
#define FSPLIT 5           // 98*5 = 490 blocks ~ 512 CU-slots (4% tail waste)
#define S_WC ((size_t)KD * OP2)   // 2,809,856
#define NFRAG_H (NP * 16 * MFRAG) // 5488 fragments per table for k_h

typedef __attribute__((ext_vector_type(4))) float f32x4;
typedef __attribute__((ext_vector_type(8))) short bf16x8;
typedef __attribute__((ext_vector_type(4))) unsigned int u32v4;

#define MFMA16 __builtin_amdgcn_mfma_f32_16x16x32_bf16

typedef __attribute__((address_space(1))) const unsigned int guint;
typedef __attribute__((address_space(3))) unsigned int luint;
#define GLL16(G, L) __builtin_amdgcn_global_load_lds((guint*)(G), (luint*)(L), 16, 0, 0)

// ---- 2-way split of an fp32 pair: hi = trunc-bf16(v), mid = RN-bf16(v-hi).
#define SPLIT2PK(V0, V1, HW, MW)                                       \
  {                                                                    \
    unsigned u0_ = __float_as_uint(V0), u1_ = __float_as_uint(V1);     \
    HW = (u0_ >> 16) | (u1_ & 0xffff0000u);                            \
    float r0_ = (V0) - __uint_as_float(u0_ & 0xffff0000u);             \
    float r1_ = (V1) - __uint_as_float(u1_ & 0xffff0000u);             \
    unsigned m0_ = __float_as_uint(r0_), m1_ = __float_as_uint(r1_);   \
    m0_ += 0x7fffu + ((m0_ >> 16) & 1u);                               \
    m1_ += 0x7fffu + ((m1_ >> 16) & 1u);                               \
    MW = (m0_ >> 16) | (m1_ & 0xffff0000u);                            \
  }

// ---- cheap variant: hi trunc, mid = trunc-bf16(v-hi); |rho| <= 2^-16|v| ----
#define SPLIT2T(V0, V1, HW, MW)                                        \
  {                                                                    \
    unsigned u0_ = __float_as_uint(V0), u1_ = __float_as_uint(V1);     \
    HW = (u0_ >> 16) | (u1_ & 0xffff0000u);                            \
    float r0_ = (V0) - __uint_as_float(u0_ & 0xffff0000u);             \
    float r1_ = (V1) - __uint_as_float(u1_ & 0xffff0000u);             \
    MW = (__float_as_uint(r0_) >> 16) |                                \
         (__float_as_uint(r1_) & 0xffff0000u);                         \
  }

// ---- exact 3-way truncation split (24-bit mantissa = 8+8+8) ----
#define SPLIT3PK(V0, V1, HW, MW, LW)                                   \
  {                                                                    \
    unsigned u0_ = __float_as_uint(V0), u1_ = __float_as_uint(V1);     \
    HW = (u0_ >> 16) | (u1_ & 0xffff0000u);                            \
    float r0_ = (V0) - __uint_as_float(u0_ & 0xffff0000u);             \
    float r1_ = (V1) - __uint_as_float(u1_ & 0xffff0000u);             \
    unsigned m0_ = __float_as_uint(r0_), m1_ = __float_as_uint(r1_);   \
    MW = (m0_ >> 16) | (m1_ & 0xffff0000u);                            \
    float s0_ = r0_ - __uint_as_float(m0_ & 0xffff0000u);              \
    float s1_ = r1_ - __uint_as_float(m1_ & 0xffff0000u);              \
    LW = (__float_as_uint(s0_) >> 16) |                                \
         (__float_as_uint(s1_) & 0xffff0000u);                         \
  }

// ---------------- A-tables: L=[l_w;s_w] -> MFMA A-frags, 2-way split -------
// Ahi[(mf*128 + s)*64 + lane] = 8 bf16 = A[o=mf*16+(l&15)][f=s*32+(l>>4)*8+j]
__global__ void k_lt(const float* __restrict__ lw, const float* __restrict__ sw,
                     u32v4* __restrict__ Ahi, u32v4* __restrict__ Amd) {
    int t = blockIdx.x * 256 + threadIdx.x;
    if (t >= MFRAG * NSTEP_TOT * 64) return;
    int lane = t & 63;
    int wv = t >> 6;                 // (mf*128 + s)
    int s = wv & 127, mf = wv >> 7;
    int o = mf * 16 + (lane & 15);
    int f0 = s * 32 + (lane >> 4) * 8;
    float v[8];
    const float* row = nullptr;
    if (o < 80) row = lw + (size_t)o * FDIM;
    else if (o < NO) row = sw + (size_t)(o - 80) * FDIM;
    #pragma unroll
    for (int j = 0; j < 8; ++j) v[j] = row ? row[f0 + j] : 0.f;
    u32v4 hw, mw;
    #pragma unroll
    for (int w = 0; w < 4; ++w)
        SPLIT2PK(v[2 * w], v[2 * w + 1], hw[w], mw[w]);
    Ahi[(size_t)wv * 64 + lane] = hw;
    Amd[(size_t)wv * 64 + lane] = mw;
}

// ---------------- integral image, c-major, padded stride 768 ---------------
__global__ void k_integral(const float* __restrict__ fm, float* __restrict__ I) {
    int gtid = blockIdx.x * blockDim.x + threadIdx.x;
    int wid = gtid >> 6;
    int lane = gtid & 63;
    if (wid >= BATCH * CH) return;
    const float* src = fm + (size_t)wid * (HFD * HFD);
    float* dst = I + (size_t)wid * IRCP2;
    if (lane < IW) dst[lane] = 0.f;
    if (lane >= 1 && lane < IW) dst[lane * IW] = 0.f;
    int c = lane;
    float acc = 0.f;
    for (int r = 0; r < HFD; ++r) {
        float v = (c < HFD) ? src[r * HFD + c] : 0.f;
        #pragma unroll
        for (int d = 1; d < 32; d <<= 1) {
            float t = __shfl_up(v, d, 64);
            if (lane >= d) v += t;
        }
        acc += v;
        if (c < HFD) dst[(r + 1) * IW + (c + 1)] = acc;
    }
}

// ---------------- bias'[o] = L[o]·fc_b + {l_b|s_b}[o] ----------------------
__global__ void k_bias(const float* __restrict__ lw, const float* __restrict__ sw,
                       const float* __restrict__ fcb, const float* __restrict__ lb,
                       const float* __restrict__ sb, float* __restrict__ bias) {
    int o = blockIdx.x;
    __shared__ float red[256];
    float s = 0.f;
    if (o < NO) {
        const float* row = (o < 80) ? (lw + (size_t)o * FDIM) : (sw + (size_t)(o - 80) * FDIM);
        for (int f = threadIdx.x; f < FDIM; f += 256) s += row[f] * fcb[f];
    }
    red[threadIdx.x] = s;
    __syncthreads();
    for (int st = 128; st > 0; st >>= 1) {
        if ((int)threadIdx.x < st) red[threadIdx.x] += red[threadIdx.x + st];
        __syncthreads();
    }
    if (threadIdx.x == 0) {
        float bv = 0.f;
        if (o < 80) bv = red[0] + lb[o];
        else if (o < NO) bv = red[0] + sb[o - 80];
        bias[o] = bv;
    }
}

// ---------------- Wc partials via MFMA, LDS-staged, counted-vmcnt pipeline -
// Wcp[fs][k][o] = sum_{f in chunk fs} L[o][f] * W1[f][k]
// grid (98, 5), 4 waves, 2 blocks/CU, balanced 490 blocks (round-12).
// NEW (T3/T4): raw s_barrier + s_waitcnt vmcnt(8) instead of __syncthreads —
// __syncthreads drains vmcnt(0), serializing the NEXT tile's prefetch with
// compute every step. Schedule: compute(g) -> barrier (readers done) ->
// stage(g+2) into tile-g's buffer -> vmcnt(8) (own stage(g+1) landed; g+2's
// 8 loads stay in flight across the barrier) -> barrier -> compute(g+1).
// Per-wave vmcnt counts its OWN 8 GLL16s/stage; barrier extends to all waves.
// (round-8 lesson: never cross-block-reduce via dense atomics.)
#define WC_STAGE(G, DB)                                                       \
  {                                                                           \
    const float* gb_ = W1 + (size_t)((G) * 32 + w) * KD + k0;                 \
    _Pragma("unroll")                                                         \
    for (int i_ = 0; i_ < 8; ++i_) {                                          \
      unsigned gc_ = (lb16 ^ ((unsigned)(i_ >> 1) << 6)) >> 2;                \
      GLL16(gb_ + (size_t)(4 * i_) * KD + gc_,                                \
            &Bs[DB][i_ * 1024 + w * 256]);                                    \
    }                                                                         \
  }

#define WC_STEP(G, DB)                                                        \
  {                                                                           \
    u32v4 ah[MFRAG], am[MFRAG];                                               \
    _Pragma("unroll")                                                         \
    for (int mf = 0; mf < MFRAG; ++mf) {                                      \
      size_t ai = (size_t)((mf * 128 + (G)) * 64 + lane);                     \
      ah[mf] = Ahi[ai]; am[mf] = Amd[ai];                                     \
    }                                                                         \
    const char* bs_ = (const char*)&Bs[DB][0];                                \
    _Pragma("unroll")                                                         \
    for (int nf = 0; nf < 4; ++nf) {                                          \
      float bv[8];                                                            \
      _Pragma("unroll")                                                       \
      for (int j = 0; j < 8; ++j)                                             \
        bv[j] = *(const float*)(bs_ + (rowg * 8 + j) * 1024 + kb[nf]);        \
      u32v4 bhw, bmw;                                                         \
      _Pragma("unroll")                                                       \
      for (int w_ = 0; w_ < 4; ++w_)                                          \
        SPLIT2T(bv[2 * w_], bv[2 * w_ + 1], bhw[w_], bmw[w_]);                \
      bf16x8 bh = __builtin_bit_cast(bf16x8, bhw);                            \
      bf16x8 bm = __builtin_bit_cast(bf16x8, bmw);                            \
      _Pragma("unroll")                                                       \
      for (int mf = 0; mf < MFRAG; ++mf) {                                    \
        bf16x8 a_h = __builtin_bit_cast(bf16x8, ah[mf]);                      \
        bf16x8 a_m = __builtin_bit_cast(bf16x8, am[mf]);                      \
        acc[mf][nf] = MFMA16(a_h, bh, acc[mf][nf], 0, 0, 0);                  \
        acc[mf][nf] = MFMA16(a_m, bh, acc[mf][nf], 0, 0, 0);                  \
        acc[mf][nf] = MFMA16(a_h, bm, acc[mf][nf], 0, 0, 0);                  \
      }                                                                       \
    }                                                                         \
  }

__global__ void __launch_bounds__(256, 2) k_wc(const float* __restrict__ W1,
                                               const u32v4* __restrict__ Ahi,
                                               const u32v4* __restrict__ Amd,
                                               float* __restrict__ Wcp) {
    __shared__ float Bs[2][32 * 256];
    int lane = threadIdx.x & 63;
    int w = threadIdx.x >> 6;        // wave 0..3
    int kblk = blockIdx.x;           // 0..97
    int fs = blockIdx.y;             // 0..4
    int k0 = kblk * 256;
    int col = lane & 15, rowg = lane >> 4;
    unsigned lb16 = (unsigned)lane * 16;

    int gstart = (fs * NSTEP_TOT) / FSPLIT;
    int gend = ((fs + 1) * NSTEP_TOT) / FSPLIT;

    unsigned kb[4];
    #pragma unroll
    for (int nf = 0; nf < 4; ++nf)
        kb[nf] = ((unsigned)((w * 64 + nf * 16 + col) * 4)) ^ ((unsigned)rowg << 6);

    f32x4 acc[MFRAG][4];
    #pragma unroll
    for (int mf = 0; mf < MFRAG; ++mf)
        #pragma unroll
        for (int nf = 0; nf < 4; ++nf)
            acc[mf][nf] = (f32x4){0.f, 0.f, 0.f, 0.f};

    // Prologue: two stages in flight, wait only for the first.
    WC_STAGE(gstart, 0);
    if (gstart + 1 < gend) {
        WC_STAGE(gstart + 1, 1);
        asm volatile("s_waitcnt vmcnt(8)" ::: "memory");
    } else {
        asm volatile("s_waitcnt vmcnt(0)" ::: "memory");
    }
    __builtin_amdgcn_sched_barrier(0);
    __builtin_amdgcn_s_barrier();
    __builtin_amdgcn_sched_barrier(0);

    for (int g = gstart; g < gend; ++g) {
        int db = (g - gstart) & 1;
        WC_STEP(g, db);
        __builtin_amdgcn_sched_barrier(0);
        __builtin_amdgcn_s_barrier();        // all waves done reading tile g
        __builtin_amdgcn_sched_barrier(0);
        if (g + 2 < gend) {
            WC_STAGE(g + 2, db);             // overwrite tile g's buffer
            asm volatile("s_waitcnt vmcnt(8)" ::: "memory");  // stage(g+1) done
        } else if (g + 1 < gend) {
            asm volatile("s_waitcnt vmcnt(0)" ::: "memory");  // last prefetch
        }
        if (g + 1 < gend) {
            __builtin_amdgcn_sched_barrier(0);
            __builtin_amdgcn_s_barrier();    // tile g+1 visible to all waves
            __builtin_amdgcn_sched_barrier(0);
        }
    }

    float* wp = Wcp + (size_t)fs * S_WC;
    #pragma unroll
    for (int mf = 0; mf < MFRAG; ++mf)
        #pragma unroll
        for (int nf = 0; nf < 4; ++nf) {
            size_t k = (size_t)k0 + w * 64 + nf * 16 + col;
            int o = mf * 16 + (rowg << 2);
            *(f32x4*)(wp + k * OP2 + o) = acc[mf][nf];
        }
}

// ---------------- fused: reduce 5 f-chunks + 3-way split -> k_h A-tables ---
// Whi[((p*16+cs)*7+mf)*64 + lane] = 8 bf16 = Wc[c=cs*32+(l>>4)*8+j][o=mf*16+(l&15)]
__global__ void k_redsplit(const float* __restrict__ Wcp, u32v4* __restrict__ Whi,
                           u32v4* __restrict__ Wmd, u32v4* __restrict__ Wlo) {
    int t = blockIdx.x * 256 + threadIdx.x;   // over NFRAG_H*64
    int lane = t & 63;
    int fi = t >> 6;
    int p = fi / (16 * MFRAG);
    int rem = fi - p * (16 * MFRAG);
    int cs = rem / MFRAG, mf = rem - cs * MFRAG;
    int o = mf * 16 + (lane & 15);
    int c0 = cs * 32 + (lane >> 4) * 8;
    float v[8];
    #pragma unroll
    for (int j = 0; j < 8; ++j) {
        size_t base = ((size_t)(c0 + j) * NP + p) * OP2 + o;
        float s = 0.f;
        #pragma unroll
        for (int i = 0; i < FSPLIT; ++i) s += Wcp[base + (size_t)i * S_WC];
        v[j] = s;
    }
    u32v4 hw, mw, lww;
    #pragma unroll
    for (int w = 0; w < 4; ++w)
        SPLIT3PK(v[2 * w], v[2 * w + 1], hw[w], mw[w], lww[w]);
    Whi[(size_t)fi * 64 + lane] = hw;
    Wmd[(size_t)fi * 64 + lane] = mw;
    Wlo[(size_t)fi * 64 + lane] = lww;
}

// ---------------- H[b][p][rc][o] = sum_c Wc[c*49+p][o] * I[b][c][rc] -------
// MFMA, 6-product (H feeds corner-difference cancellation -> need ~2^-24 rel).
#define KH_STEP(CUR, NXT, S)                                                  \
  {                                                                           \
    if ((S) + 1 < 16) {                                                       \
      _Pragma("unroll")                                                       \
      for (int nf = 0; nf < 2; ++nf)                                          \
        _Pragma("unroll")                                                     \
        for (int j = 0; j < 8; ++j)                                           \
          NXT[nf][j] = Ib[(size_t)(((S) + 1) * 32 + rowg * 8 + j) * IRCP2 + nf * 16]; \
    }                                                                         \
    bf16x8 bh[2], bm[2], bl[2];                                               \
    _Pragma("unroll")                                                         \
    for (int nf = 0; nf < 2; ++nf) {                                          \
      u32v4 bhw, bmw, blw;                                                    \
      _Pragma("unroll")                                                       \
      for (int w_ = 0; w_ < 4; ++w_)                                          \
        SPLIT3PK(CUR[nf][2 * w_], CUR[nf][2 * w_ + 1], bhw[w_], bmw[w_], blw[w_]); \
      bh[nf] = __builtin_bit_cast(bf16x8, bhw);                               \
      bm[nf] = __builtin_bit_cast(bf16x8, bmw);                               \
      bl[nf] = __builtin_bit_cast(bf16x8, blw);                               \
    }                                                                         \
    _Pragma("unroll")                                                         \
    for (int mf = 0; mf < MFRAG; ++mf) {                                      \
      size_t ai = (size_t)(((p * 16 + (S)) * MFRAG + mf) * 64 + lane);        \
      bf16x8 a_h = __builtin_bit_cast(bf16x8, Whi[ai]);                       \
      bf16x8 a_m = __builtin_bit_cast(bf16x8, Wmd[ai]);                       \
      bf16x8 a_l = __builtin_bit_cast(bf16x8, Wlo[ai]);                       \
      _Pragma("unroll")                                                       \
      for (int nf = 0; nf < 2; ++nf) {                                        \
        acc[mf][nf] = MFMA16(a_h, bh[nf], acc[mf][nf], 0, 0, 0);              \
        acc[mf][nf] = MFMA16(a_m, bh[nf], acc[mf][nf], 0, 0, 0);              \
        acc[mf][nf] = MFMA16(a_h, bm[nf], acc[mf][nf], 0, 0, 0);              \
        acc[mf][nf] = MFMA16(a_m, bm[nf], acc[mf][nf], 0, 0, 0);              \
        acc[mf][nf] = MFMA16(a_l, bh[nf], acc[mf][nf], 0, 0, 0);              \
        acc[mf][nf] = MFMA16(a_h, bl[nf], acc[mf][nf], 0, 0, 0);              \
      }                                                                       \
    }                                                                         \
  }

__global__ void __launch_bounds__(256, 2) k_h(const float* __restrict__ I,
                                              const u32v4* __restrict__ Whi,
                                              const u32v4* __restrict__ Wmd,
                                              const u32v4* __restrict__ Wlo,
                                              float* __restrict__ H) {
    int lane = threadIdx.x & 63;
    int w = threadIdx.x >> 6;
    int rcb = blockIdx.x, p = blockIdx.y, b = blockIdx.z;
    int col = lane & 15, rowg = lane >> 4;
    int rcw = rcb * 128 + w * 32;                 // wave's rc base
    const float* Ib = I + (size_t)b * CH * IRCP2 + rcw + col;

    f32x4 acc[MFRAG][2];
    #pragma unroll
    for (int mf = 0; mf < MFRAG; ++mf) {
        acc[mf][0] = (f32x4){0.f, 0.f, 0.f, 0.f};
        acc[mf][1] = (f32x4){0.f, 0.f, 0.f, 0.f};
    }
    float ib0[2][8], ib1[2][8];
    #pragma unroll
    for (int nf = 0; nf < 2; ++nf)
        #pragma unroll
        for (int j = 0; j < 8; ++j)
            ib0[nf][j] = Ib[(size_t)(rowg * 8 + j) * IRCP2 + nf * 16];

    for (int s = 0; s < 16; s += 2) {
        KH_STEP(ib0, ib1, s);
        KH_STEP(ib1, ib0, s + 1);
    }

    #pragma unroll
    for (int mf = 0; mf < MFRAG; ++mf)
        #pragma unroll
        for (int nf = 0; nf < 2; ++nf) {
            int rc = rcw + nf * 16 + col;
            if (rc < IRC) {
                float* hp = H + (((size_t)(b * NP + p)) * IRC + rc) * OP2
                            + mf * 16 + rowg * 4;
                *(f32x4*)hp = acc[mf][nf];
            }
        }
}

// ---------------- per-box gather + bias + argmax + outputs -----------------
// 512 threads: o = t&127 (o<101 active), p-quarter = t>>7 -> 4-way LDS reduce.
__global__ void __launch_bounds__(512) k_out(const float* __restrict__ boxes,
                                             const float* __restrict__ H,
                                             const float* __restrict__ bias,
                                             float* __restrict__ out) {
    int n = blockIdx.x, b = blockIdx.y;
    int t = threadIdx.x;
    __shared__ int srs[PPOOL], sre[PPOOL], scs[PPOOL], sce[PPOOL];
    __shared__ float sinv[NP];
    __shared__ float psum[4][NO];
    __shared__ float sl[NO];
    __shared__ int smi;
    const float* bx = boxes + ((size_t)b * NBOX + n) * 4;
    if (t < PPOOL) {
        int r0 = (int)(bx[0] / 32.0f);
        int c0 = (int)(bx[1] / 32.0f);
        int r1 = (int)(bx[2] / 32.0f);
        int c1 = (int)(bx[3] / 32.0f);
        int sr = r1 - r0, sc = c1 - c0;
        srs[t] = r0 + (t * sr) / PPOOL;
        sre[t] = r0 + ((t + 1) * sr + PPOOL - 1) / PPOOL;
        scs[t] = c0 + (t * sc) / PPOOL;
        sce[t] = c0 + ((t + 1) * sc + PPOOL - 1) / PPOOL;
    }
    __syncthreads();
    if (t < NP) {
        int ph = t / PPOOL, pw = t - ph * PPOOL;
        sinv[t] = 1.0f / (float)((sre[ph] - srs[ph]) * (sce[pw] - scs[pw]));
    }
    __syncthreads();
    int o = t & 127, q = t >> 7;
    if (o < NO) {
        int p0 = q ? (12 * q + 1) : 0;       // {0,13,25,37}
        int p1 = 12 * q + 13;                // {13,25,37,49}
        float acc = 0.f;
        const float* Hb = H + (size_t)b * NP * IRC * OP2 + o;
        for (int p = p0; p < p1; ++p) {
            int ph = p / PPOOL, pw = p - ph * PPOOL;
            const float* Hp = Hb + (size_t)p * IRC * OP2;
            int re = sre[ph], rs = srs[ph], ce = sce[pw], cs = scs[pw];
            float v = Hp[(size_t)(re * IW + ce) * OP2] - Hp[(size_t)(rs * IW + ce) * OP2]
                    - Hp[(size_t)(re * IW + cs) * OP2] + Hp[(size_t)(rs * IW + cs) * OP2];
            acc += v * sinv[p];
        }
        psum[q][o] = acc;
    }
    __syncthreads();
    if (t < NO) {
        float v = psum[0][t] + psum[1][t] + psum[2][t] + psum[3][t] + bias[t];
        sl[t] = v;
        if (t >= 80)
            out[(size_t)(4 * BATCH * NBOX) + ((size_t)b * NBOX + n) * (NCLS + 1) + (t - 80)] = v;
    }
    __syncthreads();
    if (t == 0) {
        float best = sl[80]; int mi = 0;
        for (int s = 1; s <= NCLS; ++s) {
            float v = sl[80 + s];
            if (v > best) { best = v; mi = s; }
        }
        smi = mi;
    }
    __syncthreads();
    if (t < 4) out[((size_t)b * NBOX + n) * 4 + t] = sl[smi + t];
}

extern "C" void kernel_launch(void* const* d_in, const int* in_sizes, int n_in,
                              void* d_out, int out_size, void* d_ws, size_t ws_size,
                              hipStream_t stream) {
    const float* fm    = (const float*)d_in[0];
    const float* boxes = (const float*)d_in[1];
    const float* fcw   = (const float*)d_in[2];
    const float* fcb   = (const float*)d_in[3];
    const float* lw    = (const float*)d_in[4];
    const float* lb    = (const float*)d_in[5];
    const float* sw    = (const float*)d_in[6];
    const float* sb    = (const float*)d_in[7];
    float* out = (float*)d_out;

    float* ws = (float*)d_ws;
    float* I    = ws;                                        // 786,432 f
    u32v4* Ahi  = (u32v4*)(I + (size_t)BATCH * CH * IRCP2);  // 57,344 frag-words
    u32v4* Amd  = Ahi + MFRAG * NSTEP_TOT * 64;
    float* bias = (float*)(Amd + MFRAG * NSTEP_TOT * 64);    // 128 f
    float* Wcp  = bias + 128;                                // 5 * S_WC f (56 MB)
    u32v4* Whi  = (u32v4*)(Wcp + (size_t)FSPLIT * S_WC);     // 351,232 frag-words
    u32v4* Wmd  = Whi + (size_t)NFRAG_H * 64;
    u32v4* Wlo  = Wmd + (size_t)NFRAG_H * 64;
    float* H    = (float*)(Wlo + (size_t)NFRAG_H * 64);      // 7,419,392 f
    // total ws ~= 108 MB

    hipLaunchKernelGGL(k_lt, dim3(224), dim3(256), 0, stream, lw, sw, Ahi, Amd);
    hipLaunchKernelGGL(k_integral, dim3(256), dim3(256), 0, stream, fm, I);
    hipLaunchKernelGGL(k_bias, dim3(104), dim3(256), 0, stream, lw, sw, fcb, lb, sb, bias);
    hipLaunchKernelGGL(k_wc, dim3(98, FSPLIT), dim3(256), 0, stream, fcw, Ahi, Amd, Wcp);
    hipLaunchKernelGGL(k_redsplit, dim3(NFRAG_H * 64 / 256), dim3(256), 0, stream, Wcp, Whi, Wmd, Wlo);
    hipLaunchKernelGGL(k_h, dim3(6, NP, BATCH), dim3(256), 0, stream, I, Whi, Wmd, Wlo, H);
    hipLaunchKernelGGL(k_out, dim3(NBOX, BATCH), dim3(512), 0, stream, boxes, H, bias, out);
}